// Round 2
// 610.501 us; speedup vs baseline: 1.1374x; 1.1374x over previous
//
#include <hip/hip_runtime.h>
#include <cmath>

#define B_ 4
#define S_ 1024
#define H_ 1024

typedef short bf16x8 __attribute__((ext_vector_type(8)));
typedef float f32x4 __attribute__((ext_vector_type(4)));
typedef _Float16 half4 __attribute__((ext_vector_type(4)));

__device__ __forceinline__ unsigned short f2bf(float f) {
  unsigned u = __float_as_uint(f);
  u += 0x7fff + ((u >> 16) & 1);  // RTNE
  return (unsigned short)(u >> 16);
}
__device__ __forceinline__ float bf2f(unsigned short h) {
  return __uint_as_float(((unsigned)h) << 16);
}
__device__ __forceinline__ void gld16(const void* g, void* l) {
  __builtin_amdgcn_global_load_lds(
      (const __attribute__((address_space(1))) unsigned int*)g,
      (__attribute__((address_space(3))) unsigned int*)l, 16, 0, 0);
}

// ---------------------------------------------------------------- gating ----
__global__ __launch_bounds__(64) void gate_kernel(
    const float* __restrict__ x, const float* __restrict__ Wg,
    float* __restrict__ gw) {
  int t = blockIdx.x;
  int lane = threadIdx.x;
  const float* xr = x + (size_t)t * H_;
  float a0 = 0.f, a1 = 0.f, a2 = 0.f, a3 = 0.f;
  for (int h = lane; h < H_; h += 64) {
    float xv = xr[h];
    const float* wr = Wg + h * 4;
    a0 += xv * wr[0]; a1 += xv * wr[1]; a2 += xv * wr[2]; a3 += xv * wr[3];
  }
  for (int off = 32; off > 0; off >>= 1) {
    a0 += __shfl_down(a0, off);
    a1 += __shfl_down(a1, off);
    a2 += __shfl_down(a2, off);
    a3 += __shfl_down(a3, off);
  }
  if (lane == 0) {
    float v[4] = {a0, a1, a2, a3};
    int i0 = 0; float b0 = v[0];
    for (int e = 1; e < 4; ++e) if (v[e] > b0) { b0 = v[e]; i0 = e; }
    int i1 = -1; float b1 = -INFINITY;
    for (int e = 0; e < 4; ++e) { if (e == i0) continue; if (v[e] > b1) { b1 = v[e]; i1 = e; } }
    float e1v = expf(b1 - b0);
    float w0 = 1.f / (1.f + e1v);
    float w1 = e1v / (1.f + e1v);
    float o[4] = {0.f, 0.f, 0.f, 0.f};
    o[i0] = w0; o[i1] = w1;
    float* g = gw + t * 4;
    g[0] = o[0]; g[1] = o[1]; g[2] = o[2]; g[3] = o[3];
  }
}

// -------------------------------------------------------- fp32 -> bf16 ------
__global__ __launch_bounds__(256) void conv_kernel(
    const float* __restrict__ src, unsigned short* __restrict__ dst,
    int nsrc, int ldsrc) {
  int idx = blockIdx.x * 256 + threadIdx.x;
  int m = idx >> 10, c = idx & 1023;
  dst[idx] = (c < nsrc) ? f2bf(src[(size_t)m * ldsrc + c]) : (unsigned short)0;
}

// --------------------- weight transpose + bf16, 4 matrices in one launch ----
__global__ __launch_bounds__(256) void wtrans4_kernel(
    const float* __restrict__ s0, const float* __restrict__ s1,
    const float* __restrict__ s2, const float* __restrict__ s3,
    unsigned short* __restrict__ d0, unsigned short* __restrict__ d1,
    unsigned short* __restrict__ d2, unsigned short* __restrict__ d3, int pd) {
  __shared__ float tile[32][33];
  int z = blockIdx.z;
  const float* src = (z == 0) ? s0 : (z == 1) ? s1 : (z == 2) ? s2 : s3;
  unsigned short* dst = (z == 0) ? d0 : (z == 1) ? d1 : (z == 2) ? d2 : d3;
  int ksrc = (z < 3) ? 1024 : pd;
  int nsrc = (z < 3) ? pd : 1024;
  int ldsrc = (z < 3) ? pd : 1024;
  int k0 = blockIdx.x * 32, n0 = blockIdx.y * 32;
  int tx = threadIdx.x & 31, ty = threadIdx.x >> 5;
  for (int i = 0; i < 32; i += 8) {
    int k = k0 + ty + i, n = n0 + tx;
    tile[ty + i][tx] = (k < ksrc && n < nsrc) ? src[(size_t)k * ldsrc + n] : 0.f;
  }
  __syncthreads();
  for (int i = 0; i < 32; i += 8) {
    int n = n0 + ty + i, k = k0 + tx;
    dst[(size_t)n * 1024 + k] = f2bf(tile[tx][ty + i]);
  }
}

// ------------------------------------------------------- bf16 MFMA GEMM -----
__global__ __launch_bounds__(256) void gemm_mfma(
    const unsigned short* __restrict__ A, const unsigned short* __restrict__ Bt,
    const float* __restrict__ b0, const float* __restrict__ b1,
    const float* __restrict__ b2, void* __restrict__ Cv, int ldc,
    int nact, int elu_ncut, int out_bf16, int mode,
    const float* __restrict__ gw, int expert, int remap,
    int qs_ncut, float qscale) {
  constexpr int K = 1024;
  __shared__ __align__(16) unsigned short As[128 * 32];
  __shared__ __align__(16) unsigned short Bs[128 * 32];
  int tid = threadIdx.x, wave = tid >> 6, lane = tid & 63;
  int quad = lane >> 4, lrow = lane & 15;
  int rw = (wave >> 1) * 64, cw = (wave & 1) * 64;
  int m0 = blockIdx.y * 128, n0 = blockIdx.x * 128;
  int srow = wave * 32 + (lane >> 2);
  int scol = (lane & 3) * 8;
  const unsigned short* gA = A + (size_t)(m0 + srow) * K + scol;
  const unsigned short* gB = Bt + (size_t)(n0 + srow) * K + scol;
  unsigned short* lA = &As[wave * 1024];
  unsigned short* lB = &Bs[wave * 1024];
  f32x4 acc[4][4];
#pragma unroll
  for (int mt = 0; mt < 4; ++mt)
#pragma unroll
    for (int nt = 0; nt < 4; ++nt) acc[mt][nt] = (f32x4){0.f, 0.f, 0.f, 0.f};

  for (int k0 = 0; k0 < K; k0 += 32) {
    gld16(gA + k0, lA);
    gld16(gA + 16 * K + k0, lA + 512);
    gld16(gB + k0, lB);
    gld16(gB + 16 * K + k0, lB + 512);
    __syncthreads();
    bf16x8 af[4], bfr[4];
#pragma unroll
    for (int t = 0; t < 4; ++t) {
      af[t]  = *(const bf16x8*)&As[(rw + t * 16 + lrow) * 32 + quad * 8];
      bfr[t] = *(const bf16x8*)&Bs[(cw + t * 16 + lrow) * 32 + quad * 8];
    }
#pragma unroll
    for (int mt = 0; mt < 4; ++mt)
#pragma unroll
      for (int nt = 0; nt < 4; ++nt)
        acc[mt][nt] = __builtin_amdgcn_mfma_f32_16x16x32_bf16(
            af[mt], bfr[nt], acc[mt][nt], 0, 0, 0);
    __syncthreads();
  }
#pragma unroll
  for (int nt = 0; nt < 4; ++nt) {
    int n = n0 + cw + nt * 16 + lrow;
    int slice = n >> 10, noff = n & 1023;
    if (noff >= nact) continue;
    const float* bp = (slice == 0) ? b0 : (slice == 1) ? b1 : b2;
    float bias = bp[noff];
    bool do_elu = n < elu_ncut;
    bool do_qs = n < qs_ncut;
    int col = n;
    if (remap) {
      int head = (noff * 12337) >> 20;  // noff/85 for noff<1020
      col = slice * 1152 + head * 96 + (noff - head * 85);
    }
#pragma unroll
    for (int mt = 0; mt < 4; ++mt) {
      int mb = m0 + rw + mt * 16 + quad * 4;
#pragma unroll
      for (int r = 0; r < 4; ++r) {
        int m = mb + r;
        float val = acc[mt][nt][r] + bias;
        if (do_elu) val = (val > 0.f) ? val + 1.f : expf(val);
        if (do_qs) val *= qscale;
        size_t ci = (size_t)m * ldc + col;
        if (out_bf16) {
          ((unsigned short*)Cv)[ci] = f2bf(val);
        } else {
          float* C = (float*)Cv;
          if (mode == 0) C[ci] = val;
          else {
            float g = gw[m * 4 + expert];
            if (mode == 1) C[ci] = g * val;
            else           C[ci] += g * val;
          }
        }
      }
    }
  }
}

// ------------------------------------- merged output projection, z=expert ---
struct OutP {
  const unsigned short* A[4];
  const unsigned short* B[4];
  const float* bias[4];
};

__global__ __launch_bounds__(256) void gemm_out4(
    OutP p, const float* __restrict__ gw, float* __restrict__ part) {
  constexpr int K = 1024;
  __shared__ __align__(16) unsigned short As[128 * 32];
  __shared__ __align__(16) unsigned short Bs[128 * 32];
  int e = blockIdx.z;
  const unsigned short* A = p.A[e];
  const unsigned short* Bt = p.B[e];
  const float* bp = p.bias[e];
  float* C = part + (size_t)e * (4096ull * 1024ull);
  int tid = threadIdx.x, wave = tid >> 6, lane = tid & 63;
  int quad = lane >> 4, lrow = lane & 15;
  int rw = (wave >> 1) * 64, cw = (wave & 1) * 64;
  int m0 = blockIdx.y * 128, n0 = blockIdx.x * 128;
  int srow = wave * 32 + (lane >> 2);
  int scol = (lane & 3) * 8;
  const unsigned short* gA = A + (size_t)(m0 + srow) * K + scol;
  const unsigned short* gB = Bt + (size_t)(n0 + srow) * K + scol;
  unsigned short* lA = &As[wave * 1024];
  unsigned short* lB = &Bs[wave * 1024];
  f32x4 acc[4][4];
#pragma unroll
  for (int mt = 0; mt < 4; ++mt)
#pragma unroll
    for (int nt = 0; nt < 4; ++nt) acc[mt][nt] = (f32x4){0.f, 0.f, 0.f, 0.f};

  for (int k0 = 0; k0 < K; k0 += 32) {
    gld16(gA + k0, lA);
    gld16(gA + 16 * K + k0, lA + 512);
    gld16(gB + k0, lB);
    gld16(gB + 16 * K + k0, lB + 512);
    __syncthreads();
    bf16x8 af[4], bfr[4];
#pragma unroll
    for (int t = 0; t < 4; ++t) {
      af[t]  = *(const bf16x8*)&As[(rw + t * 16 + lrow) * 32 + quad * 8];
      bfr[t] = *(const bf16x8*)&Bs[(cw + t * 16 + lrow) * 32 + quad * 8];
    }
#pragma unroll
    for (int mt = 0; mt < 4; ++mt)
#pragma unroll
      for (int nt = 0; nt < 4; ++nt)
        acc[mt][nt] = __builtin_amdgcn_mfma_f32_16x16x32_bf16(
            af[mt], bfr[nt], acc[mt][nt], 0, 0, 0);
    __syncthreads();
  }
#pragma unroll
  for (int nt = 0; nt < 4; ++nt) {
    int n = n0 + cw + nt * 16 + lrow;
    float bias = bp[n];
#pragma unroll
    for (int mt = 0; mt < 4; ++mt) {
      int mb = m0 + rw + mt * 16 + quad * 4;
#pragma unroll
      for (int r = 0; r < 4; ++r) {
        int m = mb + r;
        float g = gw[m * 4 + e];
        C[(size_t)m * 1024 + n] = g * (acc[mt][nt][r] + bias);
      }
    }
  }
}

// part[e] summed in expert order -> identical rounding to old mode1/mode2 chain
__global__ __launch_bounds__(256) void reduce4(
    const float* __restrict__ part, float* __restrict__ out) {
  constexpr size_t N = 4096ull * 1024ull;
  size_t idx = ((size_t)blockIdx.x * 256 + threadIdx.x) * 4;
  f32x4 a0 = *(const f32x4*)(part + idx);
  f32x4 a1 = *(const f32x4*)(part + idx + N);
  f32x4 a2 = *(const f32x4*)(part + idx + 2 * N);
  f32x4 a3 = *(const f32x4*)(part + idx + 3 * N);
  f32x4 s;
#pragma unroll
  for (int j = 0; j < 4; ++j) {
    float t = a0[j];
    t += a1[j]; t += a2[j]; t += a3[j];
    s[j] = t;
  }
  *(f32x4*)(out + idx) = s;
}

// ----- zero never-written pad columns (e1 head-pad 85..95, aob1 1020..1023) -
__global__ __launch_bounds__(256) void padzero(
    unsigned short* __restrict__ qkv1, unsigned short* __restrict__ aob1) {
  int idx = blockIdx.x * 256 + threadIdx.x;  // grid covers 4096*396 exactly
  int m = idx / 396, r = idx % 396;
  int slice = r / 132, r2 = r % 132;
  int head = r2 / 11, c = 85 + r2 % 11;
  qkv1[(size_t)m * 3456 + slice * 1152 + head * 96 + c] = 0;
  if (idx < 4096 * 4) {
    int mm = idx >> 2, cc = 1020 + (idx & 3);
    aob1[(size_t)mm * 1024 + cc] = 0;
  }
}

// --------------------------------------------- MFMA flash attention v3 ------
// body shared between the per-expert wrapper and the merged launch.
template <int HD, bool LOCAL>
__device__ __forceinline__ void attn_body(
    char* smem,
    const unsigned short* __restrict__ q, const unsigned short* __restrict__ k,
    const unsigned short* __restrict__ v, const int* __restrict__ amask,
    unsigned short* __restrict__ ao, int ldq, int h) {
  constexpr int HDP = (HD + 31) & ~31;  // 128 or 96
  constexpr int DCH = HDP / 32;         // 4 or 3
  constexpr int NDT = HDP / 16;         // 8 or 6
  constexpr int NCH = HDP / 8;          // 16 or 12
  constexpr int QT = 128, KT = 64;
  constexpr int KLD = HDP + 8;
  constexpr int VLD = KT + 4;
  constexpr int W2 = 32;
  unsigned short* Ks = (unsigned short*)smem;                       // KT*KLD
  _Float16* Vt = (_Float16*)(smem + (size_t)KT * KLD * 2);          // HDP*VLD
  unsigned long long* amq =
      (unsigned long long*)(smem + (size_t)KT * KLD * 2 + (size_t)HDP * VLD * 2);
  int tid = threadIdx.x, wave = tid >> 6, lane = tid & 63;
  int quad = lane >> 4, l15 = lane & 15;
  int q0 = blockIdx.x * QT, b = blockIdx.z;
  size_t baseq = ((size_t)b * S_) * ldq + (size_t)h * HDP;
  size_t baseo = ((size_t)b * S_) * H_ + (size_t)h * HD;

  {
    unsigned long long bb0 = __ballot(amask[b * S_ + wave * 128 + lane] != 0);
    unsigned long long bb1 = __ballot(amask[b * S_ + wave * 128 + 64 + lane] != 0);
    if (lane == 0) { amq[wave * 2] = bb0; amq[wave * 2 + 1] = bb1; }
  }

  int qrow = q0 + wave * 16 + l15;
  bf16x8 qf[DCH];
#pragma unroll
  for (int c = 0; c < DCH; ++c)
#pragma unroll
    for (int j = 0; j < 8; ++j) {
      int d = c * 32 + quad * 8 + j;
      qf[c][j] = (d < HD) ? (short)q[baseq + (size_t)qrow * ldq + d] : (short)0;
    }

  int jlo = 0, jhi = S_;
  if (LOCAL) {
    jlo = q0 - W2; if (jlo < 0) jlo = 0; jlo &= ~(KT - 1);
    jhi = q0 + QT + W2; if (jhi > S_) jhi = S_;
  }

  int skey = tid & 63, sc8a = tid >> 6, sc8b = 8 + (tid >> 6);
  bool sactb = sc8b < NCH;
  const unsigned short* kg = k + baseq + (size_t)skey * ldq;
  const unsigned short* vg = v + baseq + (size_t)skey * ldq;
  bf16x8 kra = {}, krb = {}, vra = {}, vrb = {};
  {
    size_t o = (size_t)jlo * ldq;
    kra = *(const bf16x8*)(kg + o + sc8a * 8);
    vra = *(const bf16x8*)(vg + o + sc8a * 8);
    if (sactb) {
      krb = *(const bf16x8*)(kg + o + sc8b * 8);
      vrb = *(const bf16x8*)(vg + o + sc8b * 8);
    }
  }

  float m_run = -1e30f, l_run = 0.f;
  f32x4 accd[NDT];
#pragma unroll
  for (int dt = 0; dt < NDT; ++dt) accd[dt] = (f32x4){0.f, 0.f, 0.f, 0.f};

  for (int j0 = jlo; j0 < jhi; j0 += KT) {
    __syncthreads();
    *(bf16x8*)&Ks[skey * KLD + sc8a * 8] = kra;
#pragma unroll
    for (int j = 0; j < 8; ++j)
      Vt[(sc8a * 8 + j) * VLD + skey] = (_Float16)bf2f((unsigned short)vra[j]);
    if (sactb) {
      *(bf16x8*)&Ks[skey * KLD + sc8b * 8] = krb;
#pragma unroll
      for (int j = 0; j < 8; ++j)
        Vt[(sc8b * 8 + j) * VLD + skey] = (_Float16)bf2f((unsigned short)vrb[j]);
    }
    __syncthreads();
    int jn = j0 + KT;
    if (jn < jhi) {
      size_t o = (size_t)jn * ldq;
      kra = *(const bf16x8*)(kg + o + sc8a * 8);
      vra = *(const bf16x8*)(vg + o + sc8a * 8);
      if (sactb) {
        krb = *(const bf16x8*)(kg + o + sc8b * 8);
        vrb = *(const bf16x8*)(vg + o + sc8b * 8);
      }
    }
    f32x4 sf[4];
#pragma unroll
    for (int kt = 0; kt < 4; ++kt) {
      sf[kt] = (f32x4){0.f, 0.f, 0.f, 0.f};
#pragma unroll
      for (int c = 0; c < DCH; ++c) {
        bf16x8 kf = *(const bf16x8*)&Ks[(kt * 16 + l15) * KLD + c * 32 + quad * 8];
        sf[kt] = __builtin_amdgcn_mfma_f32_16x16x32_bf16(kf, qf[c], sf[kt], 0, 0, 0);
      }
    }
    unsigned long long mb = amq[j0 >> 6];
    unsigned mw[2] = {(unsigned)mb, (unsigned)(mb >> 32)};
    float sval[4][4];
    bool vld[4][4];
    float mx = -1e30f;
#pragma unroll
    for (int kt = 0; kt < 4; ++kt) {
      unsigned word = mw[kt >> 1];
      int sh = (kt & 1) * 16 + quad * 4;
#pragma unroll
      for (int r = 0; r < 4; ++r) {
        bool ok = (word >> (sh + r)) & 1;
        if (LOCAL) {
          int dj = (j0 + kt * 16 + quad * 4 + r) - qrow;
          ok = ok && (dj <= W2) && (dj >= -W2);
        }
        float s = ok ? sf[kt][r] : -1e30f;
        sval[kt][r] = s;
        vld[kt][r] = ok;
        mx = fmaxf(mx, s);
      }
    }
    mx = fmaxf(mx, __shfl_xor(mx, 16));
    mx = fmaxf(mx, __shfl_xor(mx, 32));
    float m_new = fmaxf(m_run, mx);
    float psum = 0.f;
    float pv[4][4];
#pragma unroll
    for (int kt = 0; kt < 4; ++kt)
#pragma unroll
      for (int r = 0; r < 4; ++r) {
        float p = vld[kt][r] ? __builtin_amdgcn_exp2f(sval[kt][r] - m_new) : 0.f;
        pv[kt][r] = p;
        psum += p;
      }
    psum += __shfl_xor(psum, 16);
    psum += __shfl_xor(psum, 32);
    float alpha = __builtin_amdgcn_exp2f(m_run - m_new);
    m_run = m_new;
    l_run = l_run * alpha + psum;
    float aR[4];
#pragma unroll
    for (int r = 0; r < 4; ++r)
      aR[r] = __shfl(alpha, (lane & 48) | (quad * 4 + r));
#pragma unroll
    for (int dt = 0; dt < NDT; ++dt)
#pragma unroll
      for (int r = 0; r < 4; ++r) accd[dt][r] *= aR[r];
    half4 pf[4];
#pragma unroll
    for (int kt = 0; kt < 4; ++kt)
#pragma unroll
      for (int r = 0; r < 4; ++r) pf[kt][r] = (_Float16)pv[kt][r];
#pragma unroll
    for (int dt = 0; dt < NDT; ++dt)
#pragma unroll
      for (int kt = 0; kt < 4; ++kt) {
        half4 vf = *(const half4*)&Vt[(dt * 16 + l15) * VLD + kt * 16 + quad * 4];
        accd[dt] = __builtin_amdgcn_mfma_f32_16x16x16f16(pf[kt], vf, accd[dt], 0, 0, 0);
      }
  }
  float linv = (l_run > 0.f) ? 1.f / l_run : 0.f;
  float lR[4];
#pragma unroll
  for (int r = 0; r < 4; ++r)
    lR[r] = __shfl(linv, (lane & 48) | (quad * 4 + r));
#pragma unroll
  for (int dt = 0; dt < NDT; ++dt) {
    int d = dt * 16 + l15;
    if (d >= HD) continue;
#pragma unroll
    for (int r = 0; r < 4; ++r) {
      int row = q0 + wave * 16 + quad * 4 + r;
      ao[baseo + (size_t)row * H_ + d] = f2bf(accd[dt][r] * lR[r]);
    }
  }
}

template <int HD, bool LOCAL>
__global__ __launch_bounds__(512) void attn_mfma3(
    const unsigned short* __restrict__ q, const unsigned short* __restrict__ k,
    const unsigned short* __restrict__ v, const int* __restrict__ amask,
    unsigned short* __restrict__ ao, int ldq) {
  constexpr int HDP = (HD + 31) & ~31;
  __shared__ __align__(16) char smem[64 * (HDP + 8) * 2 + HDP * 68 * 2 + 128];
  attn_body<HD, LOCAL>(smem, q, k, v, amask, ao, ldq, blockIdx.y);
}

// one launch for e0 (8 heads) + e1 (12 heads) + e3 (8 heads local):
// grid (8, 28, 4) = 896 blocks vs 256-384 per expert before.
__global__ __launch_bounds__(512) void attn_mega(
    const unsigned short* __restrict__ qkv0,
    const unsigned short* __restrict__ qkv1,
    const unsigned short* __restrict__ qkv3, const int* __restrict__ amask,
    unsigned short* __restrict__ ao0, unsigned short* __restrict__ ao1,
    unsigned short* __restrict__ ao3) {
  __shared__ __align__(16) char smem[34944];
  int y = blockIdx.y;
  if (y < 8)
    attn_body<128, false>(smem, qkv0, qkv0 + 1024, qkv0 + 2048, amask, ao0,
                          3072, y);
  else if (y < 20)
    attn_body<85, false>(smem, qkv1, qkv1 + 1152, qkv1 + 2304, amask, ao1,
                         3456, y - 8);
  else
    attn_body<128, true>(smem, qkv3, qkv3 + 1024, qkv3 + 2048, amask, ao3,
                         3072, y - 20);
}

// ------------------------------------------------------ linear attention ----
#define NSPLIT 4
__global__ __launch_bounds__(256) void linkv_mfma(
    const unsigned short* __restrict__ k, const unsigned short* __restrict__ v,
    float* __restrict__ kvp, float* __restrict__ ksump, int ld) {
  constexpr int HD = 128;
  constexpr int TLD = 34;
  __shared__ __align__(16) unsigned short Kt[HD * TLD];
  __shared__ __align__(16) unsigned short Vt[HD * TLD];
  int h = blockIdx.x, b = blockIdx.y, split = blockIdx.z;
  int bh = b * 8 + h;
  int tid = threadIdx.x, wave = tid >> 6, lane = tid & 63;
  int quad = lane >> 4, l15 = lane & 15;
  int rw = (wave >> 1) * 64, cw = (wave & 1) * 64;
  size_t base = ((size_t)b * S_) * ld + (size_t)h * HD;
  int s_begin = split * (S_ / NSPLIT);

  f32x4 acc[4][4];
#pragma unroll
  for (int mt = 0; mt < 4; ++mt)
#pragma unroll
    for (int nt = 0; nt < 4; ++nt) acc[mt][nt] = (f32x4){0.f, 0.f, 0.f, 0.f};
  float ksacc = 0.f;
  int myd = tid & 127, half = tid >> 7;

  for (int c0 = 0; c0 < S_ / NSPLIT; c0 += 32) {
    for (int idx = tid; idx < 32 * HD; idx += 256) {
      int d = idx & 127, s = idx >> 7;
      size_t g = base + (size_t)(s_begin + c0 + s) * ld + d;
      Kt[d * TLD + s] = k[g];
      Vt[d * TLD + s] = v[g];
    }
    __syncthreads();
    bf16x8 af[4], bf[4];
#pragma unroll
    for (int t = 0; t < 4; ++t) {
      af[t] = *(const bf16x8*)&Vt[(rw + t * 16 + l15) * TLD + quad * 8];
      bf[t] = *(const bf16x8*)&Kt[(cw + t * 16 + l15) * TLD + quad * 8];
    }
#pragma unroll
    for (int mt = 0; mt < 4; ++mt)
#pragma unroll
      for (int nt = 0; nt < 4; ++nt)
        acc[mt][nt] = __builtin_amdgcn_mfma_f32_16x16x32_bf16(
            af[mt], bf[nt], acc[mt][nt], 0, 0, 0);
#pragma unroll
    for (int s = 0; s < 16; ++s)
      ksacc += bf2f(Kt[myd * TLD + half * 16 + s]);
    __syncthreads();
  }
  float* red = (float*)Kt;
  if (half == 1) red[myd] = ksacc;
  __syncthreads();
  if (half == 0)
    ksump[((size_t)split * 32 + bh) * HD + myd] = ksacc + red[myd];
  float* kvo = kvp + ((size_t)split * 32 + bh) * (HD * HD);
#pragma unroll
  for (int mt = 0; mt < 4; ++mt)
#pragma unroll
    for (int nt = 0; nt < 4; ++nt) {
      int dk = cw + nt * 16 + l15;
#pragma unroll
      for (int r = 0; r < 4; ++r) {
        int dv = rw + mt * 16 + quad * 4 + r;
        kvo[(size_t)dv * HD + dk] = acc[mt][nt][r];
      }
    }
}

__global__ __launch_bounds__(256) void linkv_reduce(
    const float* __restrict__ kvp, const float* __restrict__ ksump,
    unsigned short* __restrict__ kvb, float* __restrict__ ksum) {
  int idx = blockIdx.x * 256 + threadIdx.x;
  float s = 0.f;
#pragma unroll
  for (int p = 0; p < NSPLIT; ++p) s += kvp[(size_t)p * (32 * 128 * 128) + idx];
  kvb[idx] = f2bf(s);
  if (idx < 32 * 128) {
    float t = 0.f;
#pragma unroll
    for (int p = 0; p < NSPLIT; ++p) t += ksump[(size_t)p * (32 * 128) + idx];
    ksum[idx] = t;
  }
}

__global__ __launch_bounds__(256) void linattn_mfma(
    const unsigned short* __restrict__ q, const unsigned short* __restrict__ kvT,
    const float* __restrict__ ksum, unsigned short* __restrict__ ao, int ldq) {
  constexpr int KLD = 136;
  __shared__ __align__(16) unsigned short Ks[128 * KLD];
  __shared__ float ksL[128];
  int tid = threadIdx.x, wave = tid >> 6, lane = tid & 63;
  int quad = lane >> 4, l15 = lane & 15;
  int rw = (wave >> 1) * 64, cw = (wave & 1) * 64;
  int q0 = blockIdx.x * 128, h = blockIdx.y, b = blockIdx.z;
  int bh = b * 8 + h;
  size_t baseq = ((size_t)b * S_) * ldq + (size_t)h * 128;
  size_t baseo = ((size_t)b * S_) * H_ + (size_t)h * 128;
  const unsigned short* kvg = kvT + (size_t)bh * (128 * 128);
  for (int idx = tid; idx < 128 * 16; idx += 256) {
    int e = idx >> 4, c = idx & 15;
    *(bf16x8*)&Ks[e * KLD + c * 8] = *(const bf16x8*)&kvg[e * 128 + c * 8];
  }
  if (tid < 128) ksL[tid] = ksum[(size_t)bh * 128 + tid];
  bf16x8 qf[4][4];
#pragma unroll
  for (int mt = 0; mt < 4; ++mt) {
    const unsigned short* qr = q + baseq + (size_t)(q0 + rw + mt * 16 + l15) * ldq;
#pragma unroll
    for (int kc = 0; kc < 4; ++kc)
      qf[mt][kc] = *(const bf16x8*)&qr[kc * 32 + quad * 8];
  }
  __syncthreads();
  f32x4 acc[4][4];
#pragma unroll
  for (int mt = 0; mt < 4; ++mt)
#pragma unroll
    for (int nt = 0; nt < 4; ++nt) acc[mt][nt] = (f32x4){0.f, 0.f, 0.f, 0.f};
#pragma unroll
  for (int kc = 0; kc < 4; ++kc) {
    bf16x8 bf[4];
#pragma unroll
    for (int nt = 0; nt < 4; ++nt)
      bf[nt] = *(const bf16x8*)&Ks[(cw + nt * 16 + l15) * KLD + kc * 32 + quad * 8];
#pragma unroll
    for (int mt = 0; mt < 4; ++mt)
#pragma unroll
      for (int nt = 0; nt < 4; ++nt)
        acc[mt][nt] = __builtin_amdgcn_mfma_f32_16x16x32_bf16(
            qf[mt][kc], bf[nt], acc[mt][nt], 0, 0, 0);
  }
  float den[4];
#pragma unroll
  for (int mt = 0; mt < 4; ++mt) {
    float s = 0.f;
#pragma unroll
    for (int kc = 0; kc < 4; ++kc)
#pragma unroll
      for (int j = 0; j < 8; ++j)
        s += bf2f((unsigned short)qf[mt][kc][j]) * ksL[kc * 32 + quad * 8 + j];
    s += __shfl_xor(s, 16);
    s += __shfl_xor(s, 32);
    den[mt] = s;
  }
#pragma unroll
  for (int mt = 0; mt < 4; ++mt)
#pragma unroll
    for (int r = 0; r < 4; ++r) {
      float dv = __shfl(den[mt], (lane & 48) | (quad * 4 + r));
      float inv = 1.f / (dv + 1e-6f);
      int row = q0 + rw + mt * 16 + quad * 4 + r;
#pragma unroll
      for (int nt = 0; nt < 4; ++nt) {
        int col = cw + nt * 16 + l15;
        ao[baseo + (size_t)row * H_ + col] = f2bf(acc[mt][nt][r] * inv);
      }
    }
}

// ---------------------------------------------------------------- launch ----
extern "C" void kernel_launch(void* const* d_in, const int* in_sizes, int n_in,
                              void* d_out, int out_size, void* d_ws, size_t ws_size,
                              hipStream_t stream) {
  const float* x = (const float*)d_in[0];
  const float* Wg = (const float*)d_in[1];
  const int* amask = (const int*)d_in[34];
  float* out = (float*)d_out;
  char* ws = (char*)d_ws;
  const size_t MiB = 1ull << 20;
  const int nhs[4] = {8, 12, 8, 8};
  const float LOG2E = 1.4426950408889634f;

  if (ws_size >= 157 * MiB) {
    // ---- merged schedule. Aliasing plan (all stream-ordered, no overlap of
    // live ranges):
    //   kvp   @ 4 MiB  (8 MiB)  over xb    — xb dead after last QKV GEMM
    //   ksump @ 12 MiB (64 KB)  over qkvT  — qkvT dead after last QKV GEMM
    //   part  @ 26 MiB (64 MiB) over qkvE[0..2] — dead after attn_mega/linattn
    // aobE[*] (125..157 MiB) is ALIAS-FREE: padzero'd cols survive the frame.
    float* gw = (float*)ws;                                  // 64 KB
    float* ksum = (float*)(ws + (64ull << 10));              // 16 KB
    unsigned short* kvb = (unsigned short*)(ws + 1 * MiB);   // 1 MiB
    unsigned short* xb = (unsigned short*)(ws + 4 * MiB);    // 8 MiB
    float* kvp = (float*)(ws + 4 * MiB);                     // 8 MiB (alias xb)
    unsigned short* qkvT = (unsigned short*)(ws + 12 * MiB); // 6 MiB
    float* ksump = (float*)(ws + 12 * MiB);                  // 64 KB (alias qkvT)
    unsigned short* woT[4];
    for (int e = 0; e < 4; ++e)
      woT[e] = (unsigned short*)(ws + (18 + 2 * e) * MiB);   // 8 MiB
    const size_t qkvOff[4] = {26 * MiB, 50 * MiB, 77 * MiB, 101 * MiB};
    unsigned short* qkvE[4];
    for (int e = 0; e < 4; ++e) qkvE[e] = (unsigned short*)(ws + qkvOff[e]);
    float* part = (float*)(ws + 26 * MiB);                   // 64 MiB (alias qkvE)
    unsigned short* aobE[4];
    for (int e = 0; e < 4; ++e)
      aobE[e] = (unsigned short*)(ws + (125 + 8 * e) * MiB); // 32 MiB total

    conv_kernel<<<16384, 256, 0, stream>>>(x, xb, 1024, 1024);
    gate_kernel<<<4096, 64, 0, stream>>>(x, Wg, gw);
    padzero<<<6336, 256, 0, stream>>>(qkvE[1], aobE[1]);

    for (int e = 0; e < 4; ++e) {
      const float* Wq = (const float*)d_in[2 + 8 * e + 0];
      const float* bq = (const float*)d_in[2 + 8 * e + 1];
      const float* Wk = (const float*)d_in[2 + 8 * e + 2];
      const float* bk = (const float*)d_in[2 + 8 * e + 3];
      const float* Wv = (const float*)d_in[2 + 8 * e + 4];
      const float* bv = (const float*)d_in[2 + 8 * e + 5];
      const float* Wo = (const float*)d_in[2 + 8 * e + 6];
      int nh = nhs[e];
      int hd = H_ / nh;
      int pd = nh * hd;
      int ldqkv = (e == 1) ? 3456 : 3072;
      int qs_ncut = (e == 2) ? 0 : 1024;
      float qscale = LOG2E / sqrtf((float)hd);

      wtrans4_kernel<<<dim3(32, 32, 4), 256, 0, stream>>>(
          Wq, Wk, Wv, Wo, qkvT, qkvT + (1 << 20), qkvT + (2 << 20), woT[e], pd);

      gemm_mfma<<<dim3(24, 32), 256, 0, stream>>>(
          xb, qkvT, bq, bk, bv, qkvE[e], ldqkv,
          (pd == 1020) ? 1020 : 1024, (e == 2) ? 2048 : 0, 1, 0, nullptr, 0,
          (e == 1) ? 1 : 0, qs_ncut, qscale);
    }

    // linear-attention expert (e2); kvp/ksump clobber xb/qkvT (both dead now)
    linkv_mfma<<<dim3(8, B_, NSPLIT), 256, 0, stream>>>(
        qkvE[2] + 1024, qkvE[2] + 2048, kvp, ksump, 3072);
    linkv_reduce<<<(32 * 128 * 128) / 256, 256, 0, stream>>>(kvp, ksump, kvb, ksum);
    linattn_mfma<<<dim3(S_ / 128, 8, B_), 256, 0, stream>>>(
        qkvE[2], kvb, ksum, aobE[2], 3072);

    attn_mega<<<dim3(S_ / 128, 28, B_), 512, 0, stream>>>(
        qkvE[0], qkvE[1], qkvE[3], amask, aobE[0], aobE[1], aobE[3]);

    OutP p;
    for (int e = 0; e < 4; ++e) {
      p.A[e] = aobE[e];
      p.B[e] = woT[e];
      p.bias[e] = (const float*)d_in[2 + 8 * e + 7];
    }
    gemm_out4<<<dim3(8, 32, 4), 256, 0, stream>>>(p, gw, part);
    reduce4<<<4096, 256, 0, stream>>>(part, out);
    return;
  }

  // ---- fallback: original sequential schedule (74 MiB workspace) ----
  float* gw            = (float*)(ws + 0);
  unsigned short* kvb  = (unsigned short*)(ws + (1ull << 20));
  float* ksum          = (float*)(ws + (3ull << 20) + (1ull << 19));
  unsigned short* xb   = (unsigned short*)(ws + (4ull << 20));
  unsigned short* qkvT = (unsigned short*)(ws + (12ull << 20));
  unsigned short* woT  = (unsigned short*)(ws + (18ull << 20));
  unsigned short* qkv  = (unsigned short*)(ws + (20ull << 20));
  unsigned short* aob  = (unsigned short*)(ws + (49ull << 20));
  float* kvp           = (float*)(ws + (57ull << 20));
  float* ksump         = (float*)(ws + (73ull << 20));

  conv_kernel<<<16384, 256, 0, stream>>>(x, xb, 1024, 1024);
  gate_kernel<<<4096, 64, 0, stream>>>(x, Wg, gw);

  for (int e = 0; e < 4; ++e) {
    const float* Wq = (const float*)d_in[2 + 8 * e + 0];
    const float* bq = (const float*)d_in[2 + 8 * e + 1];
    const float* Wk = (const float*)d_in[2 + 8 * e + 2];
    const float* bk = (const float*)d_in[2 + 8 * e + 3];
    const float* Wv = (const float*)d_in[2 + 8 * e + 4];
    const float* bv = (const float*)d_in[2 + 8 * e + 5];
    const float* Wo = (const float*)d_in[2 + 8 * e + 6];
    const float* bo = (const float*)d_in[2 + 8 * e + 7];
    int nh = nhs[e];
    int hd = H_ / nh;
    int pd = nh * hd;
    int ldqkv = (e == 1) ? 3456 : 3072;
    int qs_ncut = (e == 2) ? 0 : 1024;
    float qscale = LOG2E / sqrtf((float)hd);

    wtrans4_kernel<<<dim3(32, 32, 4), 256, 0, stream>>>(
        Wq, Wk, Wv, Wo, qkvT, qkvT + (1 << 20), qkvT + (2 << 20), woT, pd);

    gemm_mfma<<<dim3(24, 32), 256, 0, stream>>>(
        xb, qkvT, bq, bk, bv, qkv, ldqkv,
        (pd == 1020) ? 1020 : 1024, (e == 2) ? 2048 : 0, 1, 0, nullptr, 0,
        (e == 1) ? 1 : 0, qs_ncut, qscale);

    if (e == 2) {
      const unsigned short* qb = qkv;
      const unsigned short* kb = qkv + 1024;
      const unsigned short* vb = qkv + 2048;
      linkv_mfma<<<dim3(8, B_, NSPLIT), 256, 0, stream>>>(kb, vb, kvp, ksump, 3072);
      linkv_reduce<<<(32 * 128 * 128) / 256, 256, 0, stream>>>(kvp, ksump, kvb, ksum);
      linattn_mfma<<<dim3(S_ / 128, 8, B_), 256, 0, stream>>>(qb, kvb, ksum, aob, 3072);
    } else if (e == 1) {
      attn_mfma3<85, false><<<dim3(S_ / 128, 12, B_), 512, 0, stream>>>(
          qkv, qkv + 1152, qkv + 2304, amask, aob, 3456);
    } else if (e == 3) {
      attn_mfma3<128, true><<<dim3(S_ / 128, 8, B_), 512, 0, stream>>>(
          qkv, qkv + 1024, qkv + 2048, amask, aob, 3072);
    } else {
      attn_mfma3<128, false><<<dim3(S_ / 128, 8, B_), 512, 0, stream>>>(
          qkv, qkv + 1024, qkv + 2048, amask, aob, 3072);
    }

    gemm_mfma<<<dim3(8, 32), 256, 0, stream>>>(
        aob, woT, bo, bo, bo, out, 1024, 1024, 0, 0, (e == 0) ? 1 : 2, gw, e, 0,
        0, 1.0f);
  }
}

// Round 3
// 593.557 us; speedup vs baseline: 1.1698x; 1.0285x over previous
//
#include <hip/hip_runtime.h>
#include <cmath>

#define B_ 4
#define S_ 1024
#define H_ 1024

typedef short bf16x8 __attribute__((ext_vector_type(8)));
typedef float f32x4 __attribute__((ext_vector_type(4)));
typedef _Float16 half4 __attribute__((ext_vector_type(4)));

__device__ __forceinline__ unsigned short f2bf(float f) {
  unsigned u = __float_as_uint(f);
  u += 0x7fff + ((u >> 16) & 1);  // RTNE
  return (unsigned short)(u >> 16);
}
__device__ __forceinline__ float bf2f(unsigned short h) {
  return __uint_as_float(((unsigned)h) << 16);
}
__device__ __forceinline__ void gld16(const void* g, void* l) {
  __builtin_amdgcn_global_load_lds(
      (const __attribute__((address_space(1))) unsigned int*)g,
      (__attribute__((address_space(3))) unsigned int*)l, 16, 0, 0);
}

// ---------------------------------------------------------------- gating ----
__global__ __launch_bounds__(64) void gate_kernel(
    const float* __restrict__ x, const float* __restrict__ Wg,
    float* __restrict__ gw) {
  int t = blockIdx.x;
  int lane = threadIdx.x;
  const float* xr = x + (size_t)t * H_;
  float a0 = 0.f, a1 = 0.f, a2 = 0.f, a3 = 0.f;
  for (int h = lane; h < H_; h += 64) {
    float xv = xr[h];
    const float* wr = Wg + h * 4;
    a0 += xv * wr[0]; a1 += xv * wr[1]; a2 += xv * wr[2]; a3 += xv * wr[3];
  }
  for (int off = 32; off > 0; off >>= 1) {
    a0 += __shfl_down(a0, off);
    a1 += __shfl_down(a1, off);
    a2 += __shfl_down(a2, off);
    a3 += __shfl_down(a3, off);
  }
  if (lane == 0) {
    float v[4] = {a0, a1, a2, a3};
    int i0 = 0; float b0 = v[0];
    for (int e = 1; e < 4; ++e) if (v[e] > b0) { b0 = v[e]; i0 = e; }
    int i1 = -1; float b1 = -INFINITY;
    for (int e = 0; e < 4; ++e) { if (e == i0) continue; if (v[e] > b1) { b1 = v[e]; i1 = e; } }
    float e1v = expf(b1 - b0);
    float w0 = 1.f / (1.f + e1v);
    float w1 = e1v / (1.f + e1v);
    float o[4] = {0.f, 0.f, 0.f, 0.f};
    o[i0] = w0; o[i1] = w1;
    float* g = gw + t * 4;
    g[0] = o[0]; g[1] = o[1]; g[2] = o[2]; g[3] = o[3];
  }
}

// -------------------------------------------------------- fp32 -> bf16 ------
__global__ __launch_bounds__(256) void conv_kernel(
    const float* __restrict__ src, unsigned short* __restrict__ dst,
    int nsrc, int ldsrc) {
  int idx = blockIdx.x * 256 + threadIdx.x;
  int m = idx >> 10, c = idx & 1023;
  dst[idx] = (c < nsrc) ? f2bf(src[(size_t)m * ldsrc + c]) : (unsigned short)0;
}

// --------------------- weight transpose + bf16, 4 matrices in one launch ----
__global__ __launch_bounds__(256) void wtrans4_kernel(
    const float* __restrict__ s0, const float* __restrict__ s1,
    const float* __restrict__ s2, const float* __restrict__ s3,
    unsigned short* __restrict__ d0, unsigned short* __restrict__ d1,
    unsigned short* __restrict__ d2, unsigned short* __restrict__ d3, int pd) {
  __shared__ float tile[32][33];
  int z = blockIdx.z;
  const float* src = (z == 0) ? s0 : (z == 1) ? s1 : (z == 2) ? s2 : s3;
  unsigned short* dst = (z == 0) ? d0 : (z == 1) ? d1 : (z == 2) ? d2 : d3;
  int ksrc = (z < 3) ? 1024 : pd;
  int nsrc = (z < 3) ? pd : 1024;
  int ldsrc = (z < 3) ? pd : 1024;
  int k0 = blockIdx.x * 32, n0 = blockIdx.y * 32;
  int tx = threadIdx.x & 31, ty = threadIdx.x >> 5;
  for (int i = 0; i < 32; i += 8) {
    int k = k0 + ty + i, n = n0 + tx;
    tile[ty + i][tx] = (k < ksrc && n < nsrc) ? src[(size_t)k * ldsrc + n] : 0.f;
  }
  __syncthreads();
  for (int i = 0; i < 32; i += 8) {
    int n = n0 + ty + i, k = k0 + tx;
    dst[(size_t)n * 1024 + k] = f2bf(tile[tx][ty + i]);
  }
}

// ------------------------------------------------------- bf16 MFMA GEMM -----
__global__ __launch_bounds__(256) void gemm_mfma(
    const unsigned short* __restrict__ A, const unsigned short* __restrict__ Bt,
    const float* __restrict__ b0, const float* __restrict__ b1,
    const float* __restrict__ b2, void* __restrict__ Cv, int ldc,
    int nact, int elu_ncut, int out_bf16, int mode,
    const float* __restrict__ gw, int expert, int remap,
    int qs_ncut, float qscale) {
  constexpr int K = 1024;
  __shared__ __align__(16) unsigned short As[128 * 32];
  __shared__ __align__(16) unsigned short Bs[128 * 32];
  int tid = threadIdx.x, wave = tid >> 6, lane = tid & 63;
  int quad = lane >> 4, lrow = lane & 15;
  int rw = (wave >> 1) * 64, cw = (wave & 1) * 64;
  int m0 = blockIdx.y * 128, n0 = blockIdx.x * 128;
  int srow = wave * 32 + (lane >> 2);
  int scol = (lane & 3) * 8;
  const unsigned short* gA = A + (size_t)(m0 + srow) * K + scol;
  const unsigned short* gB = Bt + (size_t)(n0 + srow) * K + scol;
  unsigned short* lA = &As[wave * 1024];
  unsigned short* lB = &Bs[wave * 1024];
  f32x4 acc[4][4];
#pragma unroll
  for (int mt = 0; mt < 4; ++mt)
#pragma unroll
    for (int nt = 0; nt < 4; ++nt) acc[mt][nt] = (f32x4){0.f, 0.f, 0.f, 0.f};

  for (int k0 = 0; k0 < K; k0 += 32) {
    gld16(gA + k0, lA);
    gld16(gA + 16 * K + k0, lA + 512);
    gld16(gB + k0, lB);
    gld16(gB + 16 * K + k0, lB + 512);
    __syncthreads();
    bf16x8 af[4], bfr[4];
#pragma unroll
    for (int t = 0; t < 4; ++t) {
      af[t]  = *(const bf16x8*)&As[(rw + t * 16 + lrow) * 32 + quad * 8];
      bfr[t] = *(const bf16x8*)&Bs[(cw + t * 16 + lrow) * 32 + quad * 8];
    }
#pragma unroll
    for (int mt = 0; mt < 4; ++mt)
#pragma unroll
      for (int nt = 0; nt < 4; ++nt)
        acc[mt][nt] = __builtin_amdgcn_mfma_f32_16x16x32_bf16(
            af[mt], bfr[nt], acc[mt][nt], 0, 0, 0);
    __syncthreads();
  }
#pragma unroll
  for (int nt = 0; nt < 4; ++nt) {
    int n = n0 + cw + nt * 16 + lrow;
    int slice = n >> 10, noff = n & 1023;
    if (noff >= nact) continue;
    const float* bp = (slice == 0) ? b0 : (slice == 1) ? b1 : b2;
    float bias = bp[noff];
    bool do_elu = n < elu_ncut;
    bool do_qs = n < qs_ncut;
    int col = n;
    if (remap) {
      int head = (noff * 12337) >> 20;  // noff/85 for noff<1020
      col = slice * 1152 + head * 96 + (noff - head * 85);
    }
#pragma unroll
    for (int mt = 0; mt < 4; ++mt) {
      int mb = m0 + rw + mt * 16 + quad * 4;
#pragma unroll
      for (int r = 0; r < 4; ++r) {
        int m = mb + r;
        float val = acc[mt][nt][r] + bias;
        if (do_elu) val = (val > 0.f) ? val + 1.f : expf(val);
        if (do_qs) val *= qscale;
        size_t ci = (size_t)m * ldc + col;
        if (out_bf16) {
          ((unsigned short*)Cv)[ci] = f2bf(val);
        } else {
          float* C = (float*)Cv;
          if (mode == 0) C[ci] = val;
          else {
            float g = gw[m * 4 + expert];
            if (mode == 1) C[ci] = g * val;
            else           C[ci] += g * val;
          }
        }
      }
    }
  }
}

// ------------------------------------- merged output projection, z=expert ---
struct OutP {
  const unsigned short* A[4];
  const unsigned short* B[4];
  const float* bias[4];
};

__global__ __launch_bounds__(256) void gemm_out4(
    OutP p, const float* __restrict__ gw, float* __restrict__ part) {
  constexpr int K = 1024;
  __shared__ __align__(16) unsigned short As[128 * 32];
  __shared__ __align__(16) unsigned short Bs[128 * 32];
  int e = blockIdx.z;
  const unsigned short* A = p.A[e];
  const unsigned short* Bt = p.B[e];
  const float* bp = p.bias[e];
  float* C = part + (size_t)e * (4096ull * 1024ull);
  int tid = threadIdx.x, wave = tid >> 6, lane = tid & 63;
  int quad = lane >> 4, lrow = lane & 15;
  int rw = (wave >> 1) * 64, cw = (wave & 1) * 64;
  int m0 = blockIdx.y * 128, n0 = blockIdx.x * 128;
  int srow = wave * 32 + (lane >> 2);
  int scol = (lane & 3) * 8;
  const unsigned short* gA = A + (size_t)(m0 + srow) * K + scol;
  const unsigned short* gB = Bt + (size_t)(n0 + srow) * K + scol;
  unsigned short* lA = &As[wave * 1024];
  unsigned short* lB = &Bs[wave * 1024];
  f32x4 acc[4][4];
#pragma unroll
  for (int mt = 0; mt < 4; ++mt)
#pragma unroll
    for (int nt = 0; nt < 4; ++nt) acc[mt][nt] = (f32x4){0.f, 0.f, 0.f, 0.f};

  for (int k0 = 0; k0 < K; k0 += 32) {
    gld16(gA + k0, lA);
    gld16(gA + 16 * K + k0, lA + 512);
    gld16(gB + k0, lB);
    gld16(gB + 16 * K + k0, lB + 512);
    __syncthreads();
    bf16x8 af[4], bfr[4];
#pragma unroll
    for (int t = 0; t < 4; ++t) {
      af[t]  = *(const bf16x8*)&As[(rw + t * 16 + lrow) * 32 + quad * 8];
      bfr[t] = *(const bf16x8*)&Bs[(cw + t * 16 + lrow) * 32 + quad * 8];
    }
#pragma unroll
    for (int mt = 0; mt < 4; ++mt)
#pragma unroll
      for (int nt = 0; nt < 4; ++nt)
        acc[mt][nt] = __builtin_amdgcn_mfma_f32_16x16x32_bf16(
            af[mt], bfr[nt], acc[mt][nt], 0, 0, 0);
    __syncthreads();
  }
#pragma unroll
  for (int nt = 0; nt < 4; ++nt) {
    int n = n0 + cw + nt * 16 + lrow;
    float bias = bp[n];
#pragma unroll
    for (int mt = 0; mt < 4; ++mt) {
      int mb = m0 + rw + mt * 16 + quad * 4;
#pragma unroll
      for (int r = 0; r < 4; ++r) {
        int m = mb + r;
        float g = gw[m * 4 + e];
        C[(size_t)m * 1024 + n] = g * (acc[mt][nt][r] + bias);
      }
    }
  }
}

// part[e] summed in expert order -> identical rounding to old mode1/mode2 chain
__global__ __launch_bounds__(256) void reduce4(
    const float* __restrict__ part, float* __restrict__ out) {
  constexpr size_t N = 4096ull * 1024ull;
  size_t idx = ((size_t)blockIdx.x * 256 + threadIdx.x) * 4;
  f32x4 a0 = *(const f32x4*)(part + idx);
  f32x4 a1 = *(const f32x4*)(part + idx + N);
  f32x4 a2 = *(const f32x4*)(part + idx + 2 * N);
  f32x4 a3 = *(const f32x4*)(part + idx + 3 * N);
  f32x4 s;
#pragma unroll
  for (int j = 0; j < 4; ++j) {
    float t = a0[j];
    t += a1[j]; t += a2[j]; t += a3[j];
    s[j] = t;
  }
  *(f32x4*)(out + idx) = s;
}

// ----- zero never-written pad columns (e1 head-pad 85..95, aob1 1020..1023) -
__global__ __launch_bounds__(256) void padzero(
    unsigned short* __restrict__ qkv1, unsigned short* __restrict__ aob1) {
  int idx = blockIdx.x * 256 + threadIdx.x;  // grid covers 4096*396 exactly
  int m = idx / 396, r = idx % 396;
  int slice = r / 132, r2 = r % 132;
  int head = r2 / 11, c = 85 + r2 % 11;
  qkv1[(size_t)m * 3456 + slice * 1152 + head * 96 + c] = 0;
  if (idx < 4096 * 4) {
    int mm = idx >> 2, cc = 1020 + (idx & 3);
    aob1[(size_t)mm * 1024 + cc] = 0;
  }
}

// --------------------------------------------- MFMA flash attention v4 ------
// QT=256: each wave owns TWO 16-row groups; every Ks/Vt LDS read (kf/vf) is
// shared across both groups -> LDS bytes and global K/V re-reads per output
// row are HALVED vs v3 (LDS-BW-bound per round-2 counters).
template <int HD, bool LOCAL>
__device__ __forceinline__ void attn_body(
    char* smem,
    const unsigned short* __restrict__ q, const unsigned short* __restrict__ k,
    const unsigned short* __restrict__ v, const int* __restrict__ amask,
    unsigned short* __restrict__ ao, int ldq, int h) {
  constexpr int HDP = (HD + 31) & ~31;  // 128 or 96
  constexpr int DCH = HDP / 32;         // 4 or 3
  constexpr int NDT = HDP / 16;         // 8 or 6
  constexpr int NCH = HDP / 8;          // 16 or 12
  constexpr int QT = 256, KT = 64;
  constexpr int KLD = HDP + 8;
  constexpr int VLD = KT + 4;
  constexpr int W2 = 32;
  unsigned short* Ks = (unsigned short*)smem;                       // KT*KLD
  _Float16* Vt = (_Float16*)(smem + (size_t)KT * KLD * 2);          // HDP*VLD
  unsigned long long* amq =
      (unsigned long long*)(smem + (size_t)KT * KLD * 2 + (size_t)HDP * VLD * 2);
  int tid = threadIdx.x, wave = tid >> 6, lane = tid & 63;
  int quad = lane >> 4, l15 = lane & 15;
  int q0 = blockIdx.x * QT, b = blockIdx.z;
  size_t baseq = ((size_t)b * S_) * ldq + (size_t)h * HDP;
  size_t baseo = ((size_t)b * S_) * H_ + (size_t)h * HD;

  {
    unsigned long long bb0 = __ballot(amask[b * S_ + wave * 128 + lane] != 0);
    unsigned long long bb1 = __ballot(amask[b * S_ + wave * 128 + 64 + lane] != 0);
    if (lane == 0) { amq[wave * 2] = bb0; amq[wave * 2 + 1] = bb1; }
  }

  int qrow[2];
  bf16x8 qf[2][DCH];
#pragma unroll
  for (int g = 0; g < 2; ++g) {
    qrow[g] = q0 + wave * 32 + g * 16 + l15;
#pragma unroll
    for (int c = 0; c < DCH; ++c)
#pragma unroll
      for (int j = 0; j < 8; ++j) {
        int d = c * 32 + quad * 8 + j;
        qf[g][c][j] =
            (d < HD) ? (short)q[baseq + (size_t)qrow[g] * ldq + d] : (short)0;
      }
  }

  int jlo = 0, jhi = S_;
  if (LOCAL) {
    jlo = q0 - W2; if (jlo < 0) jlo = 0; jlo &= ~(KT - 1);
    jhi = q0 + QT + W2; if (jhi > S_) jhi = S_;
  }

  int skey = tid & 63, sc8a = tid >> 6, sc8b = 8 + (tid >> 6);
  bool sactb = sc8b < NCH;
  const unsigned short* kg = k + baseq + (size_t)skey * ldq;
  const unsigned short* vg = v + baseq + (size_t)skey * ldq;
  bf16x8 kra = {}, krb = {}, vra = {}, vrb = {};
  {
    size_t o = (size_t)jlo * ldq;
    kra = *(const bf16x8*)(kg + o + sc8a * 8);
    vra = *(const bf16x8*)(vg + o + sc8a * 8);
    if (sactb) {
      krb = *(const bf16x8*)(kg + o + sc8b * 8);
      vrb = *(const bf16x8*)(vg + o + sc8b * 8);
    }
  }

  float m_run[2] = {-1e30f, -1e30f}, l_run[2] = {0.f, 0.f};
  f32x4 accd[2][NDT];
#pragma unroll
  for (int g = 0; g < 2; ++g)
#pragma unroll
    for (int dt = 0; dt < NDT; ++dt) accd[g][dt] = (f32x4){0.f, 0.f, 0.f, 0.f};

  for (int j0 = jlo; j0 < jhi; j0 += KT) {
    __syncthreads();
    *(bf16x8*)&Ks[skey * KLD + sc8a * 8] = kra;
#pragma unroll
    for (int j = 0; j < 8; ++j)
      Vt[(sc8a * 8 + j) * VLD + skey] = (_Float16)bf2f((unsigned short)vra[j]);
    if (sactb) {
      *(bf16x8*)&Ks[skey * KLD + sc8b * 8] = krb;
#pragma unroll
      for (int j = 0; j < 8; ++j)
        Vt[(sc8b * 8 + j) * VLD + skey] = (_Float16)bf2f((unsigned short)vrb[j]);
    }
    __syncthreads();
    int jn = j0 + KT;
    if (jn < jhi) {
      size_t o = (size_t)jn * ldq;
      kra = *(const bf16x8*)(kg + o + sc8a * 8);
      vra = *(const bf16x8*)(vg + o + sc8a * 8);
      if (sactb) {
        krb = *(const bf16x8*)(kg + o + sc8b * 8);
        vrb = *(const bf16x8*)(vg + o + sc8b * 8);
      }
    }
    // ---- S^T = K @ Q^T : kf loaded once, used for both row-groups ----
    f32x4 sf[2][4];
#pragma unroll
    for (int kt = 0; kt < 4; ++kt) {
      sf[0][kt] = (f32x4){0.f, 0.f, 0.f, 0.f};
      sf[1][kt] = (f32x4){0.f, 0.f, 0.f, 0.f};
#pragma unroll
      for (int c = 0; c < DCH; ++c) {
        bf16x8 kf = *(const bf16x8*)&Ks[(kt * 16 + l15) * KLD + c * 32 + quad * 8];
        sf[0][kt] = __builtin_amdgcn_mfma_f32_16x16x32_bf16(kf, qf[0][c], sf[0][kt], 0, 0, 0);
        sf[1][kt] = __builtin_amdgcn_mfma_f32_16x16x32_bf16(kf, qf[1][c], sf[1][kt], 0, 0, 0);
      }
    }
    unsigned long long mb = amq[j0 >> 6];
    unsigned mw[2] = {(unsigned)mb, (unsigned)(mb >> 32)};
    float pvv[2][4][4];
    float mx[2] = {-1e30f, -1e30f};
#pragma unroll
    for (int kt = 0; kt < 4; ++kt) {
      unsigned word = mw[kt >> 1];
      int sh = (kt & 1) * 16 + quad * 4;
#pragma unroll
      for (int r = 0; r < 4; ++r) {
        bool okm = (word >> (sh + r)) & 1;
#pragma unroll
        for (int g = 0; g < 2; ++g) {
          bool ok = okm;
          if (LOCAL) {
            int dj = (j0 + kt * 16 + quad * 4 + r) - qrow[g];
            ok = ok && (dj <= W2) && (dj >= -W2);
          }
          float s = ok ? sf[g][kt][r] : -1e30f;
          pvv[g][kt][r] = s;
          mx[g] = fmaxf(mx[g], s);
        }
      }
    }
    half4 pf[2][4];
    float aR[2][4];
#pragma unroll
    for (int g = 0; g < 2; ++g) {
      float mxg = fmaxf(mx[g], __shfl_xor(mx[g], 16));
      mxg = fmaxf(mxg, __shfl_xor(mxg, 32));
      float m_new = fmaxf(m_run[g], mxg);
      float psum = 0.f;
#pragma unroll
      for (int kt = 0; kt < 4; ++kt)
#pragma unroll
        for (int r = 0; r < 4; ++r) {
          float s = pvv[g][kt][r];
          float p = (s > -1e29f) ? __builtin_amdgcn_exp2f(s - m_new) : 0.f;
          pvv[g][kt][r] = p;
          psum += p;
        }
      psum += __shfl_xor(psum, 16);
      psum += __shfl_xor(psum, 32);
      float alpha = __builtin_amdgcn_exp2f(m_run[g] - m_new);
      m_run[g] = m_new;
      l_run[g] = l_run[g] * alpha + psum;
#pragma unroll
      for (int r = 0; r < 4; ++r)
        aR[g][r] = __shfl(alpha, (lane & 48) | (quad * 4 + r));
#pragma unroll
      for (int dt = 0; dt < NDT; ++dt)
#pragma unroll
        for (int r = 0; r < 4; ++r) accd[g][dt][r] *= aR[g][r];
#pragma unroll
      for (int kt = 0; kt < 4; ++kt)
#pragma unroll
        for (int r = 0; r < 4; ++r) pf[g][kt][r] = (_Float16)pvv[g][kt][r];
    }
    // ---- P^T @ V^T : vf loaded once, used for both row-groups ----
#pragma unroll
    for (int dt = 0; dt < NDT; ++dt)
#pragma unroll
      for (int kt = 0; kt < 4; ++kt) {
        half4 vf = *(const half4*)&Vt[(dt * 16 + l15) * VLD + kt * 16 + quad * 4];
        accd[0][dt] = __builtin_amdgcn_mfma_f32_16x16x16f16(pf[0][kt], vf, accd[0][dt], 0, 0, 0);
        accd[1][dt] = __builtin_amdgcn_mfma_f32_16x16x16f16(pf[1][kt], vf, accd[1][dt], 0, 0, 0);
      }
  }
#pragma unroll
  for (int g = 0; g < 2; ++g) {
    float linv = (l_run[g] > 0.f) ? 1.f / l_run[g] : 0.f;
    float lR[4];
#pragma unroll
    for (int r = 0; r < 4; ++r)
      lR[r] = __shfl(linv, (lane & 48) | (quad * 4 + r));
#pragma unroll
    for (int dt = 0; dt < NDT; ++dt) {
      int d = dt * 16 + l15;
      if (d >= HD) continue;
#pragma unroll
      for (int r = 0; r < 4; ++r) {
        int row = q0 + wave * 32 + g * 16 + quad * 4 + r;
        ao[baseo + (size_t)row * H_ + d] = f2bf(accd[g][dt][r] * lR[r]);
      }
    }
  }
}

template <int HD, bool LOCAL>
__global__ __launch_bounds__(512) void attn_mfma3(
    const unsigned short* __restrict__ q, const unsigned short* __restrict__ k,
    const unsigned short* __restrict__ v, const int* __restrict__ amask,
    unsigned short* __restrict__ ao, int ldq) {
  constexpr int HDP = (HD + 31) & ~31;
  __shared__ __align__(16) char smem[64 * (HDP + 8) * 2 + HDP * 68 * 2 + 128];
  attn_body<HD, LOCAL>(smem, q, k, v, amask, ao, ldq, blockIdx.y);
}

// one launch for e0 (8 heads) + e1 (12 heads) + e3 (8 heads local):
// grid (4, 28, 4) = 448 blocks; short e3 blocks (y>=20) dispatch last -> tail.
__global__ __launch_bounds__(512) void attn_mega(
    const unsigned short* __restrict__ qkv0,
    const unsigned short* __restrict__ qkv1,
    const unsigned short* __restrict__ qkv3, const int* __restrict__ amask,
    unsigned short* __restrict__ ao0, unsigned short* __restrict__ ao1,
    unsigned short* __restrict__ ao3) {
  __shared__ __align__(16) char smem[34944];
  int y = blockIdx.y;
  if (y < 8)
    attn_body<128, false>(smem, qkv0, qkv0 + 1024, qkv0 + 2048, amask, ao0,
                          3072, y);
  else if (y < 20)
    attn_body<85, false>(smem, qkv1, qkv1 + 1152, qkv1 + 2304, amask, ao1,
                         3456, y - 8);
  else
    attn_body<128, true>(smem, qkv3, qkv3 + 1024, qkv3 + 2048, amask, ao3,
                         3072, y - 20);
}

// ------------------------------------------------------ linear attention ----
#define NSPLIT 4
__global__ __launch_bounds__(256) void linkv_mfma(
    const unsigned short* __restrict__ k, const unsigned short* __restrict__ v,
    float* __restrict__ kvp, float* __restrict__ ksump, int ld) {
  constexpr int HD = 128;
  constexpr int TLD = 34;
  __shared__ __align__(16) unsigned short Kt[HD * TLD];
  __shared__ __align__(16) unsigned short Vt[HD * TLD];
  int h = blockIdx.x, b = blockIdx.y, split = blockIdx.z;
  int bh = b * 8 + h;
  int tid = threadIdx.x, wave = tid >> 6, lane = tid & 63;
  int quad = lane >> 4, l15 = lane & 15;
  int rw = (wave >> 1) * 64, cw = (wave & 1) * 64;
  size_t base = ((size_t)b * S_) * ld + (size_t)h * HD;
  int s_begin = split * (S_ / NSPLIT);

  f32x4 acc[4][4];
#pragma unroll
  for (int mt = 0; mt < 4; ++mt)
#pragma unroll
    for (int nt = 0; nt < 4; ++nt) acc[mt][nt] = (f32x4){0.f, 0.f, 0.f, 0.f};
  float ksacc = 0.f;
  int myd = tid & 127, half = tid >> 7;

  for (int c0 = 0; c0 < S_ / NSPLIT; c0 += 32) {
    for (int idx = tid; idx < 32 * HD; idx += 256) {
      int d = idx & 127, s = idx >> 7;
      size_t g = base + (size_t)(s_begin + c0 + s) * ld + d;
      Kt[d * TLD + s] = k[g];
      Vt[d * TLD + s] = v[g];
    }
    __syncthreads();
    bf16x8 af[4], bf[4];
#pragma unroll
    for (int t = 0; t < 4; ++t) {
      af[t] = *(const bf16x8*)&Vt[(rw + t * 16 + l15) * TLD + quad * 8];
      bf[t] = *(const bf16x8*)&Kt[(cw + t * 16 + l15) * TLD + quad * 8];
    }
#pragma unroll
    for (int mt = 0; mt < 4; ++mt)
#pragma unroll
      for (int nt = 0; nt < 4; ++nt)
        acc[mt][nt] = __builtin_amdgcn_mfma_f32_16x16x32_bf16(
            af[mt], bf[nt], acc[mt][nt], 0, 0, 0);
#pragma unroll
    for (int s = 0; s < 16; ++s)
      ksacc += bf2f(Kt[myd * TLD + half * 16 + s]);
    __syncthreads();
  }
  float* red = (float*)Kt;
  if (half == 1) red[myd] = ksacc;
  __syncthreads();
  if (half == 0)
    ksump[((size_t)split * 32 + bh) * HD + myd] = ksacc + red[myd];
  float* kvo = kvp + ((size_t)split * 32 + bh) * (HD * HD);
#pragma unroll
  for (int mt = 0; mt < 4; ++mt)
#pragma unroll
    for (int nt = 0; nt < 4; ++nt) {
      int dk = cw + nt * 16 + l15;
#pragma unroll
      for (int r = 0; r < 4; ++r) {
        int dv = rw + mt * 16 + quad * 4 + r;
        kvo[(size_t)dv * HD + dk] = acc[mt][nt][r];
      }
    }
}

__global__ __launch_bounds__(256) void linkv_reduce(
    const float* __restrict__ kvp, const float* __restrict__ ksump,
    unsigned short* __restrict__ kvb, float* __restrict__ ksum) {
  int idx = blockIdx.x * 256 + threadIdx.x;
  float s = 0.f;
#pragma unroll
  for (int p = 0; p < NSPLIT; ++p) s += kvp[(size_t)p * (32 * 128 * 128) + idx];
  kvb[idx] = f2bf(s);
  if (idx < 32 * 128) {
    float t = 0.f;
#pragma unroll
    for (int p = 0; p < NSPLIT; ++p) t += ksump[(size_t)p * (32 * 128) + idx];
    ksum[idx] = t;
  }
}

__global__ __launch_bounds__(256) void linattn_mfma(
    const unsigned short* __restrict__ q, const unsigned short* __restrict__ kvT,
    const float* __restrict__ ksum, unsigned short* __restrict__ ao, int ldq) {
  constexpr int KLD = 136;
  __shared__ __align__(16) unsigned short Ks[128 * KLD];
  __shared__ float ksL[128];
  int tid = threadIdx.x, wave = tid >> 6, lane = tid & 63;
  int quad = lane >> 4, l15 = lane & 15;
  int rw = (wave >> 1) * 64, cw = (wave & 1) * 64;
  int q0 = blockIdx.x * 128, h = blockIdx.y, b = blockIdx.z;
  int bh = b * 8 + h;
  size_t baseq = ((size_t)b * S_) * ldq + (size_t)h * 128;
  size_t baseo = ((size_t)b * S_) * H_ + (size_t)h * 128;
  const unsigned short* kvg = kvT + (size_t)bh * (128 * 128);
  for (int idx = tid; idx < 128 * 16; idx += 256) {
    int e = idx >> 4, c = idx & 15;
    *(bf16x8*)&Ks[e * KLD + c * 8] = *(const bf16x8*)&kvg[e * 128 + c * 8];
  }
  if (tid < 128) ksL[tid] = ksum[(size_t)bh * 128 + tid];
  bf16x8 qf[4][4];
#pragma unroll
  for (int mt = 0; mt < 4; ++mt) {
    const unsigned short* qr = q + baseq + (size_t)(q0 + rw + mt * 16 + l15) * ldq;
#pragma unroll
    for (int kc = 0; kc < 4; ++kc)
      qf[mt][kc] = *(const bf16x8*)&qr[kc * 32 + quad * 8];
  }
  __syncthreads();
  f32x4 acc[4][4];
#pragma unroll
  for (int mt = 0; mt < 4; ++mt)
#pragma unroll
    for (int nt = 0; nt < 4; ++nt) acc[mt][nt] = (f32x4){0.f, 0.f, 0.f, 0.f};
#pragma unroll
  for (int kc = 0; kc < 4; ++kc) {
    bf16x8 bf[4];
#pragma unroll
    for (int nt = 0; nt < 4; ++nt)
      bf[nt] = *(const bf16x8*)&Ks[(cw + nt * 16 + l15) * KLD + kc * 32 + quad * 8];
#pragma unroll
    for (int mt = 0; mt < 4; ++mt)
#pragma unroll
      for (int nt = 0; nt < 4; ++nt)
        acc[mt][nt] = __builtin_amdgcn_mfma_f32_16x16x32_bf16(
            qf[mt][kc], bf[nt], acc[mt][nt], 0, 0, 0);
  }
  float den[4];
#pragma unroll
  for (int mt = 0; mt < 4; ++mt) {
    float s = 0.f;
#pragma unroll
    for (int kc = 0; kc < 4; ++kc)
#pragma unroll
      for (int j = 0; j < 8; ++j)
        s += bf2f((unsigned short)qf[mt][kc][j]) * ksL[kc * 32 + quad * 8 + j];
    s += __shfl_xor(s, 16);
    s += __shfl_xor(s, 32);
    den[mt] = s;
  }
#pragma unroll
  for (int mt = 0; mt < 4; ++mt)
#pragma unroll
    for (int r = 0; r < 4; ++r) {
      float dv = __shfl(den[mt], (lane & 48) | (quad * 4 + r));
      float inv = 1.f / (dv + 1e-6f);
      int row = q0 + rw + mt * 16 + quad * 4 + r;
#pragma unroll
      for (int nt = 0; nt < 4; ++nt) {
        int col = cw + nt * 16 + l15;
        ao[baseo + (size_t)row * H_ + col] = f2bf(acc[mt][nt][r] * inv);
      }
    }
}

// ---------------------------------------------------------------- launch ----
extern "C" void kernel_launch(void* const* d_in, const int* in_sizes, int n_in,
                              void* d_out, int out_size, void* d_ws, size_t ws_size,
                              hipStream_t stream) {
  const float* x = (const float*)d_in[0];
  const float* Wg = (const float*)d_in[1];
  const int* amask = (const int*)d_in[34];
  float* out = (float*)d_out;
  char* ws = (char*)d_ws;
  const size_t MiB = 1ull << 20;
  const int nhs[4] = {8, 12, 8, 8};
  const float LOG2E = 1.4426950408889634f;

  if (ws_size >= 157 * MiB) {
    // ---- merged schedule. Aliasing plan (all stream-ordered, no overlap of
    // live ranges):
    //   kvp   @ 4 MiB  (8 MiB)  over xb    — xb dead after last QKV GEMM
    //   ksump @ 12 MiB (64 KB)  over qkvT  — qkvT dead after last QKV GEMM
    //   part  @ 26 MiB (64 MiB) over qkvE[0..2] — dead after attn_mega/linattn
    // aobE[*] (125..157 MiB) is ALIAS-FREE: padzero'd cols survive the frame.
    float* gw = (float*)ws;                                  // 64 KB
    float* ksum = (float*)(ws + (64ull << 10));              // 16 KB
    unsigned short* kvb = (unsigned short*)(ws + 1 * MiB);   // 1 MiB
    unsigned short* xb = (unsigned short*)(ws + 4 * MiB);    // 8 MiB
    float* kvp = (float*)(ws + 4 * MiB);                     // 8 MiB (alias xb)
    unsigned short* qkvT = (unsigned short*)(ws + 12 * MiB); // 6 MiB
    float* ksump = (float*)(ws + 12 * MiB);                  // 64 KB (alias qkvT)
    unsigned short* woT[4];
    for (int e = 0; e < 4; ++e)
      woT[e] = (unsigned short*)(ws + (18 + 2 * e) * MiB);   // 8 MiB
    const size_t qkvOff[4] = {26 * MiB, 50 * MiB, 77 * MiB, 101 * MiB};
    unsigned short* qkvE[4];
    for (int e = 0; e < 4; ++e) qkvE[e] = (unsigned short*)(ws + qkvOff[e]);
    float* part = (float*)(ws + 26 * MiB);                   // 64 MiB (alias qkvE)
    unsigned short* aobE[4];
    for (int e = 0; e < 4; ++e)
      aobE[e] = (unsigned short*)(ws + (125 + 8 * e) * MiB); // 32 MiB total

    conv_kernel<<<16384, 256, 0, stream>>>(x, xb, 1024, 1024);
    gate_kernel<<<4096, 64, 0, stream>>>(x, Wg, gw);
    padzero<<<6336, 256, 0, stream>>>(qkvE[1], aobE[1]);

    for (int e = 0; e < 4; ++e) {
      const float* Wq = (const float*)d_in[2 + 8 * e + 0];
      const float* bq = (const float*)d_in[2 + 8 * e + 1];
      const float* Wk = (const float*)d_in[2 + 8 * e + 2];
      const float* bk = (const float*)d_in[2 + 8 * e + 3];
      const float* Wv = (const float*)d_in[2 + 8 * e + 4];
      const float* bv = (const float*)d_in[2 + 8 * e + 5];
      const float* Wo = (const float*)d_in[2 + 8 * e + 6];
      int nh = nhs[e];
      int hd = H_ / nh;
      int pd = nh * hd;
      int ldqkv = (e == 1) ? 3456 : 3072;
      int qs_ncut = (e == 2) ? 0 : 1024;
      float qscale = LOG2E / sqrtf((float)hd);

      wtrans4_kernel<<<dim3(32, 32, 4), 256, 0, stream>>>(
          Wq, Wk, Wv, Wo, qkvT, qkvT + (1 << 20), qkvT + (2 << 20), woT[e], pd);

      gemm_mfma<<<dim3(24, 32), 256, 0, stream>>>(
          xb, qkvT, bq, bk, bv, qkvE[e], ldqkv,
          (pd == 1020) ? 1020 : 1024, (e == 2) ? 2048 : 0, 1, 0, nullptr, 0,
          (e == 1) ? 1 : 0, qs_ncut, qscale);
    }

    // linear-attention expert (e2); kvp/ksump clobber xb/qkvT (both dead now)
    linkv_mfma<<<dim3(8, B_, NSPLIT), 256, 0, stream>>>(
        qkvE[2] + 1024, qkvE[2] + 2048, kvp, ksump, 3072);
    linkv_reduce<<<(32 * 128 * 128) / 256, 256, 0, stream>>>(kvp, ksump, kvb, ksum);
    linattn_mfma<<<dim3(S_ / 128, 8, B_), 256, 0, stream>>>(
        qkvE[2], kvb, ksum, aobE[2], 3072);

    attn_mega<<<dim3(S_ / 256, 28, B_), 512, 0, stream>>>(
        qkvE[0], qkvE[1], qkvE[3], amask, aobE[0], aobE[1], aobE[3]);

    OutP p;
    for (int e = 0; e < 4; ++e) {
      p.A[e] = aobE[e];
      p.B[e] = woT[e];
      p.bias[e] = (const float*)d_in[2 + 8 * e + 7];
    }
    gemm_out4<<<dim3(8, 32, 4), 256, 0, stream>>>(p, gw, part);
    reduce4<<<4096, 256, 0, stream>>>(part, out);
    return;
  }

  // ---- fallback: original sequential schedule (74 MiB workspace) ----
  float* gw            = (float*)(ws + 0);
  unsigned short* kvb  = (unsigned short*)(ws + (1ull << 20));
  float* ksum          = (float*)(ws + (3ull << 20) + (1ull << 19));
  unsigned short* xb   = (unsigned short*)(ws + (4ull << 20));
  unsigned short* qkvT = (unsigned short*)(ws + (12ull << 20));
  unsigned short* woT  = (unsigned short*)(ws + (18ull << 20));
  unsigned short* qkv  = (unsigned short*)(ws + (20ull << 20));
  unsigned short* aob  = (unsigned short*)(ws + (49ull << 20));
  float* kvp           = (float*)(ws + (57ull << 20));
  float* ksump         = (float*)(ws + (73ull << 20));

  conv_kernel<<<16384, 256, 0, stream>>>(x, xb, 1024, 1024);
  gate_kernel<<<4096, 64, 0, stream>>>(x, Wg, gw);

  for (int e = 0; e < 4; ++e) {
    const float* Wq = (const float*)d_in[2 + 8 * e + 0];
    const float* bq = (const float*)d_in[2 + 8 * e + 1];
    const float* Wk = (const float*)d_in[2 + 8 * e + 2];
    const float* bk = (const float*)d_in[2 + 8 * e + 3];
    const float* Wv = (const float*)d_in[2 + 8 * e + 4];
    const float* bv = (const float*)d_in[2 + 8 * e + 5];
    const float* Wo = (const float*)d_in[2 + 8 * e + 6];
    const float* bo = (const float*)d_in[2 + 8 * e + 7];
    int nh = nhs[e];
    int hd = H_ / nh;
    int pd = nh * hd;
    int ldqkv = (e == 1) ? 3456 : 3072;
    int qs_ncut = (e == 2) ? 0 : 1024;
    float qscale = LOG2E / sqrtf((float)hd);

    wtrans4_kernel<<<dim3(32, 32, 4), 256, 0, stream>>>(
        Wq, Wk, Wv, Wo, qkvT, qkvT + (1 << 20), qkvT + (2 << 20), woT, pd);

    gemm_mfma<<<dim3(24, 32), 256, 0, stream>>>(
        xb, qkvT, bq, bk, bv, qkv, ldqkv,
        (pd == 1020) ? 1020 : 1024, (e == 2) ? 2048 : 0, 1, 0, nullptr, 0,
        (e == 1) ? 1 : 0, qs_ncut, qscale);

    if (e == 2) {
      const unsigned short* qb = qkv;
      const unsigned short* kb = qkv + 1024;
      const unsigned short* vb = qkv + 2048;
      linkv_mfma<<<dim3(8, B_, NSPLIT), 256, 0, stream>>>(kb, vb, kvp, ksump, 3072);
      linkv_reduce<<<(32 * 128 * 128) / 256, 256, 0, stream>>>(kvp, ksump, kvb, ksum);
      linattn_mfma<<<dim3(S_ / 128, 8, B_), 256, 0, stream>>>(qb, kvb, ksum, aob, 3072);
    } else if (e == 1) {
      attn_mfma3<85, false><<<dim3(S_ / 256, 12, B_), 512, 0, stream>>>(
          qkv, qkv + 1152, qkv + 2304, amask, aob, 3456);
    } else if (e == 3) {
      attn_mfma3<128, true><<<dim3(S_ / 256, 8, B_), 512, 0, stream>>>(
          qkv, qkv + 1024, qkv + 2048, amask, aob, 3072);
    } else {
      attn_mfma3<128, false><<<dim3(S_ / 256, 8, B_), 512, 0, stream>>>(
          qkv, qkv + 1024, qkv + 2048, amask, aob, 3072);
    }

    gemm_mfma<<<dim3(8, 32), 256, 0, stream>>>(
        aob, woT, bo, bo, bo, out, 1024, 1024, 0, 0, (e == 0) ? 1 : 2, gw, e, 0,
        0, 1.0f);
  }
}